// Round 9
// baseline (192.566 us; speedup 1.0000x reference)
//
#include <hip/hip_runtime.h>
#include <math.h>

#define NROWS 2000000
#define IN_DIM 64
#define HID 128
#define NTILES (NROWS / 16)   // 125000 tiles of 16 rows
#define BLOCK 256
#define NBLK 768              // 3 blocks/CU x 256 CU
#define WPB (BLOCK / 64)      // 4 waves per block

typedef _Float16 half8 __attribute__((ext_vector_type(8)));
typedef float f32x4 __attribute__((ext_vector_type(4)));

#define TWO_LOG2E 2.885390081777927f   // 2*log2(e)
#define LOG2E     1.4426950408889634f

#if __has_builtin(__builtin_amdgcn_exp2f)
#define EXP2F(x) __builtin_amdgcn_exp2f(x)
#else
#define EXP2F(x) __expf((x) * 0.6931471805599453f)
#endif

// Sum within each 16-lane group on the VALU pipe (v_add + DPP row_shr).
// Lane (c16==15) of each group ends with the total. Zero DS-pipe traffic.
__device__ __forceinline__ float dpp_row_sum16(float v) {
    int x;
    x = __float_as_int(v);
    v += __int_as_float(__builtin_amdgcn_update_dpp(0, x, 0x111, 0xf, 0xf, true));
    x = __float_as_int(v);
    v += __int_as_float(__builtin_amdgcn_update_dpp(0, x, 0x112, 0xf, 0xf, true));
    x = __float_as_int(v);
    v += __int_as_float(__builtin_amdgcn_update_dpp(0, x, 0x114, 0xf, 0xf, true));
    x = __float_as_int(v);
    v += __int_as_float(__builtin_amdgcn_update_dpp(0, x, 0x118, 0xf, 0xf, true));
    return v;
}

__global__ void zero_sums_kernel(float* g) {
    if (threadIdx.x < 2) g[threadIdx.x] = 0.0f;
}

// ROUND 9: zero LDS, zero DS ops in the loop, no barriers, no inline-asm
// waits. x and T are register-prefetched depth-1 (use distance = one full
// iteration ~2000 cyc >> HBM latency). W1 fp16 fragments live in registers.
// (256,3): 3 blocks/CU x 4 waves = 12 waves/CU = 3/SIMD -> ~168-reg cap;
// est. live set ~155 -> no spill (round-3 lesson: 2nd arg = min blocks/CU).
__global__ __launch_bounds__(BLOCK, 3) void fused_mfma_kernel(
    const float* __restrict__ x, const int* __restrict__ T,
    const float* __restrict__ W1, const float* __restrict__ b1,
    const float* __restrict__ W2, const float* __restrict__ b2,
    float* __restrict__ e_out, float* __restrict__ gsums)
{
    const int lane = threadIdx.x & 63;
    const int c16  = lane & 15;   // A-row / C-col residue
    const int g4   = lane >> 4;   // k-octet / C row-group

    // ---- W1 as fp16 B-fragments in REGISTERS (16 x half8 = 64 VGPR) ----
    // B[k][n] = W1[n][k]; lane: n = t*16 + c16, k = c*32 + g4*8 + j
    half8 wreg[8][2];
    #pragma unroll
    for (int t = 0; t < 8; t++) {
        const int n = t * 16 + c16;
        #pragma unroll
        for (int c = 0; c < 2; c++) {
            const float* wp = W1 + n * IN_DIM + c * 32 + g4 * 8;
            half8 h;
            #pragma unroll
            for (int j = 0; j < 8; j++) h[j] = (_Float16)wp[j];
            wreg[t][c] = h;
        }
    }
    // d1[t] = 2*log2(e)*b1 ; w2 raw; Sconst = sum_j W2_j + b2 (lane15-valid)
    float d1v[8], w2v[8];
    float w2loc = 0.f;
    #pragma unroll
    for (int t = 0; t < 8; t++) {
        d1v[t] = TWO_LOG2E * b1[t * 16 + c16];
        w2v[t] = W2[t * 16 + c16];
        w2loc += w2v[t];
    }
    const float SconstL = (dpp_row_sum16(w2loc) + b2[0]) * LOG2E; // lane15-valid

    const int gwave = blockIdx.x * WPB + (threadIdx.x >> 6);
    const int nwave = NBLK * WPB;     // 3072 waves, all resident

    float ls0 = 0.f, ls1 = 0.f;

    // ---- depth-1 register prefetch of x-fragments and T for tile 0 ----
    // lane (c16,g4) loads x[row = tile*16 + c16][k = g4*8 (+32)] — each
    // instr-pair covers 64B+64B of all 16 rows' lines (TA merges per line).
    int tile = gwave;
    f32x4 g0, g1, g2, g3;
    int4 tcur, tnext;
    {
        const float* xp = x + (size_t)tile * 1024 + c16 * 64 + g4 * 8;
        g0 = *(const f32x4*)(xp);
        g1 = *(const f32x4*)(xp + 4);
        g2 = *(const f32x4*)(xp + 32);
        g3 = *(const f32x4*)(xp + 36);
        if (c16 == 15) tcur = *(const int4*)&T[tile * 16 + g4 * 4];
    }

    for (; tile < NTILES; tile += nwave) {
        // consume prefetched x (compiler inserts the counted vmcnt here)
        half8 xf0, xf1;
        #pragma unroll
        for (int j = 0; j < 4; j++) {
            xf0[j]     = (_Float16)g0[j];
            xf0[4 + j] = (_Float16)g1[j];
            xf1[j]     = (_Float16)g2[j];
            xf1[4 + j] = (_Float16)g3[j];
        }

        // issue next tile's x + T loads (full iteration of latency cover)
        const int nt = tile + nwave;
        if (nt < NTILES) {
            const float* xp = x + (size_t)nt * 1024 + c16 * 64 + g4 * 8;
            g0 = *(const f32x4*)(xp);
            g1 = *(const f32x4*)(xp + 4);
            g2 = *(const f32x4*)(xp + 32);
            g3 = *(const f32x4*)(xp + 36);
            if (c16 == 15) tnext = *(const int4*)&T[nt * 16 + g4 * 4];
        }

        // ---- h = x @ W1.T : 16 fp16 MFMAs, everything in registers ----
        f32x4 acc[8];
        #pragma unroll
        for (int t = 0; t < 8; t++) acc[t] = (f32x4){0.f, 0.f, 0.f, 0.f};
        #pragma unroll
        for (int t = 0; t < 8; t++) {
            acc[t] = __builtin_amdgcn_mfma_f32_16x16x32_f16(xf0, wreg[t][0], acc[t], 0, 0, 0);
            acc[t] = __builtin_amdgcn_mfma_f32_16x16x32_f16(xf1, wreg[t][1], acc[t], 0, 0, 0);
        }

        // ---- epilogue: s = Sconst - 2*sum_j w2_j * rcp(exp2(2log2e*a_j+d1_j)+1)
        // C layout: lane holds h[row = g4*4 + r][col = t*16 + c16].
        float sp0 = 0.f, sp1 = 0.f, sp2 = 0.f, sp3 = 0.f;
        #pragma unroll
        for (int t = 0; t < 8; t++) {
            float r0 = __builtin_amdgcn_rcpf(EXP2F(fmaf(acc[t][0], TWO_LOG2E, d1v[t])) + 1.0f);
            float r1 = __builtin_amdgcn_rcpf(EXP2F(fmaf(acc[t][1], TWO_LOG2E, d1v[t])) + 1.0f);
            float r2 = __builtin_amdgcn_rcpf(EXP2F(fmaf(acc[t][2], TWO_LOG2E, d1v[t])) + 1.0f);
            float r3 = __builtin_amdgcn_rcpf(EXP2F(fmaf(acc[t][3], TWO_LOG2E, d1v[t])) + 1.0f);
            sp0 = fmaf(w2v[t], r0, sp0);
            sp1 = fmaf(w2v[t], r1, sp1);
            sp2 = fmaf(w2v[t], r2, sp2);
            sp3 = fmaf(w2v[t], r3, sp3);
        }
        sp0 = dpp_row_sum16(sp0);
        sp1 = dpp_row_sum16(sp1);
        sp2 = dpp_row_sum16(sp2);
        sp3 = dpp_row_sum16(sp3);

        if (c16 == 15) {   // 4 lanes/wave, each owns 4 consecutive rows
            const int row0 = tile * 16 + g4 * 4;
            float e0 = EXP2F(fmaf(-2.0f * sp0, LOG2E, SconstL));
            float e1 = EXP2F(fmaf(-2.0f * sp1, LOG2E, SconstL));
            float e2 = EXP2F(fmaf(-2.0f * sp2, LOG2E, SconstL));
            float e3 = EXP2F(fmaf(-2.0f * sp3, LOG2E, SconstL));
            *(f32x4*)&e_out[row0] = (f32x4){e0, e1, e2, e3};
            // tcur was prefetched a full iteration ago -> no exposed latency
            if (tcur.x == 0) ls0 += e0; else ls1 += e0;
            if (tcur.y == 0) ls0 += e1; else ls1 += e1;
            if (tcur.z == 0) ls0 += e2; else ls1 += e2;
            if (tcur.w == 0) ls0 += e3; else ls1 += e3;
        }
        tcur = tnext;
    }

    // per-wave reduce, then one atomic pair per wave (3072 waves total)
    #pragma unroll
    for (int off = 32; off > 0; off >>= 1) {
        ls0 += __shfl_down(ls0, off, 64);
        ls1 += __shfl_down(ls1, off, 64);
    }
    if (lane == 0) {
        atomicAdd(&gsums[0], ls0);
        atomicAdd(&gsums[1], ls1);
    }
}

__global__ __launch_bounds__(256) void normalize_kernel(
    float* __restrict__ e_out, const int* __restrict__ T,
    const float* __restrict__ gsums)
{
    const float inv0 = 1.0f / gsums[0];
    const float inv1 = 1.0f / gsums[1];
    const int n4 = NROWS / 4;
    const int stride = gridDim.x * blockDim.x;
    for (int i = blockIdx.x * blockDim.x + threadIdx.x; i < n4; i += stride) {
        float4 e = reinterpret_cast<const float4*>(e_out)[i];
        int4  t = reinterpret_cast<const int4*>(T)[i];
        e.x *= (t.x == 0) ? inv0 : inv1;
        e.y *= (t.y == 0) ? inv0 : inv1;
        e.z *= (t.z == 0) ? inv0 : inv1;
        e.w *= (t.w == 0) ? inv0 : inv1;
        reinterpret_cast<float4*>(e_out)[i] = e;
    }
}

extern "C" void kernel_launch(void* const* d_in, const int* in_sizes, int n_in,
                              void* d_out, int out_size, void* d_ws, size_t ws_size,
                              hipStream_t stream) {
    const float* x  = (const float*)d_in[0];
    const int*   T  = (const int*)d_in[1];
    const float* W1 = (const float*)d_in[2];
    const float* b1 = (const float*)d_in[3];
    const float* W2 = (const float*)d_in[4];
    const float* b2 = (const float*)d_in[5];
    float* e_out = (float*)d_out;
    float* gsums = (float*)d_ws;

    zero_sums_kernel<<<1, 64, 0, stream>>>(gsums);

    // 768 blocks x 256 thr = 3072 waves; NO LDS, ~155 VGPR ->
    // 3 blocks/CU, 12 waves/CU (3/SIMD), all resident.
    fused_mfma_kernel<<<NBLK, BLOCK, 0, stream>>>(x, T, W1, b1, W2, b2, e_out, gsums);

    normalize_kernel<<<2048, 256, 0, stream>>>(e_out, T, gsums);
}

// Round 10
// 166.904 us; speedup vs baseline: 1.1538x; 1.1538x over previous
//
#include <hip/hip_runtime.h>
#include <math.h>

#define NROWS 2000000
#define IN_DIM 64
#define HID 128
#define NTILES (NROWS / 16)   // 125000 tiles of 16 rows
#define BLOCK 256
#define NBLK 768              // 3 blocks/CU x 256 CU
#define WPB (BLOCK / 64)      // 4 waves per block

typedef _Float16 half8 __attribute__((ext_vector_type(8)));
typedef float f32x4 __attribute__((ext_vector_type(4)));

#define TWO_LOG2E 2.885390081777927f   // 2*log2(e)
#define LOG2E     1.4426950408889634f

#if __has_builtin(__builtin_amdgcn_exp2f)
#define EXP2F(x) __builtin_amdgcn_exp2f(x)
#else
#define EXP2F(x) __expf((x) * 0.6931471805599453f)
#endif

// Sum within each 16-lane group on the VALU pipe (v_add + DPP row_shr).
// Lane (c16==15) of each group ends with the total. Zero DS-pipe traffic.
__device__ __forceinline__ float dpp_row_sum16(float v) {
    int x;
    x = __float_as_int(v);
    v += __int_as_float(__builtin_amdgcn_update_dpp(0, x, 0x111, 0xf, 0xf, true));
    x = __float_as_int(v);
    v += __int_as_float(__builtin_amdgcn_update_dpp(0, x, 0x112, 0xf, 0xf, true));
    x = __float_as_int(v);
    v += __int_as_float(__builtin_amdgcn_update_dpp(0, x, 0x114, 0xf, 0xf, true));
    x = __float_as_int(v);
    v += __int_as_float(__builtin_amdgcn_update_dpp(0, x, 0x118, 0xf, 0xf, true));
    return v;
}

// DMA one 4KB x-tile into per-wave LDS buffer. Consecutive lane addresses
// (lane l reads base + k*1024 + l*16) -> TA merges into full-line
// transactions. ROUND-10 CHANGE: aux = 2 (gfx94x CPol NT bit): x is a
// 512MB single-use stream; NT skips L2/L3 line install so the read path
// isn't throttled by allocate/evict churn (hypothesis: that churn is the
// ~3.2 TB/s read wall seen across rounds 6-9). Cache hints cannot change
// results -> absmax must stay bit-identical.
__device__ __forceinline__ void dma_tile(const float* __restrict__ xsrc,
                                         char* dst, int lane) {
    #pragma unroll
    for (int k = 0; k < 4; k++) {
        __builtin_amdgcn_global_load_lds(
            (const __attribute__((address_space(1))) void*)(xsrc + k * 256 + lane * 4),
            (__attribute__((address_space(3))) void*)(dst + k * 1024),
            16, 0, /*aux=NT*/ 2);
    }
}

__global__ void zero_sums_kernel(float* g) {
    if (threadIdx.x < 2) g[threadIdx.x] = 0.0f;
}

// (256,3): 3 blocks/CU x 4 waves = 12 waves/CU = 3/SIMD -> ~170-reg cap.
// Est. live set ~150 -> no spill. LDS 48KB x 3 blocks = 144KB <= 160KB.
__global__ __launch_bounds__(BLOCK, 3) void fused_mfma_kernel(
    const float* __restrict__ x, const int* __restrict__ T,
    const float* __restrict__ W1, const float* __restrict__ b1,
    const float* __restrict__ W2, const float* __restrict__ b2,
    float* __restrict__ e_out, float* __restrict__ gsums)
{
    // per-wave x TRIPLE buffer: 4 waves x 3 x 4KB = 48 KB/block
    __shared__ char xbuf[WPB][3][4096];

    const int lane = threadIdx.x & 63;
    const int wv   = threadIdx.x >> 6;
    const int c16  = lane & 15;   // A-row / C-col residue
    const int g4   = lane >> 4;   // k-octet / C row-group

    // ---- W1 as fp16 B-fragments in REGISTERS (16 x half8 = 64 VGPR) ----
    // B[k][n] = W1[n][k]; lane: n = t*16 + c16, k = c*32 + g4*8 + j
    half8 wreg[8][2];
    #pragma unroll
    for (int t = 0; t < 8; t++) {
        const int n = t * 16 + c16;
        #pragma unroll
        for (int c = 0; c < 2; c++) {
            const float* wp = W1 + n * IN_DIM + c * 32 + g4 * 8;
            half8 h;
            #pragma unroll
            for (int j = 0; j < 8; j++) h[j] = (_Float16)wp[j];
            wreg[t][c] = h;
        }
    }
    // d1[t] = 2*log2(e)*b1 ; w2 raw; Sconst = sum_j W2_j + b2 (lane15-valid)
    float d1v[8], w2v[8];
    float w2loc = 0.f;
    #pragma unroll
    for (int t = 0; t < 8; t++) {
        d1v[t] = TWO_LOG2E * b1[t * 16 + c16];
        w2v[t] = W2[t * 16 + c16];
        w2loc += w2v[t];
    }
    const float SconstL = (dpp_row_sum16(w2loc) + b2[0]) * LOG2E; // lane15-valid

    char* b0 = &xbuf[wv][0][0];
    char* b1_ = &xbuf[wv][1][0];
    char* b2_ = &xbuf[wv][2][0];

    const int gwave = blockIdx.x * WPB + wv;
    const int nwave = NBLK * WPB;     // 3072 waves, all resident

    float ls0 = 0.f, ls1 = 0.f;

    // ---- depth-2 prologue ----
    int tile = gwave;
    dma_tile(x + (size_t)tile * 1024, b0, lane);               // gwave < NTILES always
    if (tile + nwave < NTILES) {
        dma_tile(x + (size_t)(tile + nwave) * 1024, b1_, lane);
        asm volatile("s_waitcnt vmcnt(4)" ::: "memory");       // b0 landed, b1 in flight
    } else {
        asm volatile("s_waitcnt vmcnt(0)" ::: "memory");       // only b0 issued
    }

    // reader offsets (LINEAR layout): row c16 (256B), k-bytes g4*32 (+128)
    const int rb = c16 * 256 + g4 * 32;
    const int o0 = rb;          // k = g4*8 .. +3
    const int o1 = rb + 16;     // k = g4*8+4 .. +7
    const int o2 = rb + 128;    // k = 32+g4*8 .. +3
    const int o3 = rb + 144;    // k = 32+g4*8+4 .. +7

    for (; tile < NTILES; tile += nwave) {
        // b0 = landed current tile
        f32x4 a0 = *(const f32x4*)(b0 + o0);
        f32x4 a1 = *(const f32x4*)(b0 + o1);
        f32x4 a2 = *(const f32x4*)(b0 + o2);
        f32x4 a3 = *(const f32x4*)(b0 + o3);

        // f32 -> fp16 A-fragments
        half8 xf0, xf1;
        #pragma unroll
        for (int j = 0; j < 4; j++) {
            xf0[j]     = (_Float16)a0[j];
            xf0[4 + j] = (_Float16)a1[j];
            xf1[j]     = (_Float16)a2[j];
            xf1[4 + j] = (_Float16)a3[j];
        }

        // ---- h = x @ W1.T : 16 fp16 MFMAs, W from registers ----
        f32x4 acc[8];
        #pragma unroll
        for (int t = 0; t < 8; t++) acc[t] = (f32x4){0.f, 0.f, 0.f, 0.f};
        #pragma unroll
        for (int t = 0; t < 8; t++) {
            acc[t] = __builtin_amdgcn_mfma_f32_16x16x32_f16(xf0, wreg[t][0], acc[t], 0, 0, 0);
            acc[t] = __builtin_amdgcn_mfma_f32_16x16x32_f16(xf1, wreg[t][1], acc[t], 0, 0, 0);
        }

        // ---- epilogue: s = Sconst - 2*sum_j w2_j * rcp(exp2(2log2e*a_j+d1_j)+1)
        // C layout: lane holds h[row = g4*4 + r][col = t*16 + c16].
        float sp0 = 0.f, sp1 = 0.f, sp2 = 0.f, sp3 = 0.f;
        #pragma unroll
        for (int t = 0; t < 8; t++) {
            float r0 = __builtin_amdgcn_rcpf(EXP2F(fmaf(acc[t][0], TWO_LOG2E, d1v[t])) + 1.0f);
            float r1 = __builtin_amdgcn_rcpf(EXP2F(fmaf(acc[t][1], TWO_LOG2E, d1v[t])) + 1.0f);
            float r2 = __builtin_amdgcn_rcpf(EXP2F(fmaf(acc[t][2], TWO_LOG2E, d1v[t])) + 1.0f);
            float r3 = __builtin_amdgcn_rcpf(EXP2F(fmaf(acc[t][3], TWO_LOG2E, d1v[t])) + 1.0f);
            sp0 = fmaf(w2v[t], r0, sp0);
            sp1 = fmaf(w2v[t], r1, sp1);
            sp2 = fmaf(w2v[t], r2, sp2);
            sp3 = fmaf(w2v[t], r3, sp3);
        }
        sp0 = dpp_row_sum16(sp0);
        sp1 = dpp_row_sum16(sp1);
        sp2 = dpp_row_sum16(sp2);
        sp3 = dpp_row_sum16(sp3);

        if (c16 == 15) {   // 4 lanes/wave, each owns 4 consecutive rows
            const int row0 = tile * 16 + g4 * 4;
            int4 t4 = *(const int4*)&T[row0];
            float e0 = EXP2F(fmaf(-2.0f * sp0, LOG2E, SconstL));
            float e1 = EXP2F(fmaf(-2.0f * sp1, LOG2E, SconstL));
            float e2 = EXP2F(fmaf(-2.0f * sp2, LOG2E, SconstL));
            float e3 = EXP2F(fmaf(-2.0f * sp3, LOG2E, SconstL));
            *(f32x4*)&e_out[row0] = (f32x4){e0, e1, e2, e3};
            if (t4.x == 0) ls0 += e0; else ls1 += e0;
            if (t4.y == 0) ls0 += e1; else ls1 += e1;
            if (t4.z == 0) ls0 += e2; else ls1 += e2;
            if (t4.w == 0) ls0 += e3; else ls1 += e3;
        }

        // ---- issue DMA for tile+2 into the free buffer, then counted wait ----
        const int nt2 = tile + 2 * nwave;
        if (nt2 < NTILES) {
            dma_tile(x + (size_t)nt2 * 1024, b2_, lane);
            // keep {store, 4 new DMA} in flight; forces tile+1's DMA landed
            asm volatile("s_waitcnt vmcnt(5)" ::: "memory");
        } else {
            // tail: nothing new issued; force tile+1's DMA landed (keep store)
            asm volatile("s_waitcnt vmcnt(1)" ::: "memory");
        }

        // rotate triple buffer
        char* tmp = b0; b0 = b1_; b1_ = b2_; b2_ = tmp;
    }

    // per-wave reduce, then one atomic pair per wave (3072 waves total)
    #pragma unroll
    for (int off = 32; off > 0; off >>= 1) {
        ls0 += __shfl_down(ls0, off, 64);
        ls1 += __shfl_down(ls1, off, 64);
    }
    if (lane == 0) {
        atomicAdd(&gsums[0], ls0);
        atomicAdd(&gsums[1], ls1);
    }
}

__global__ __launch_bounds__(256) void normalize_kernel(
    float* __restrict__ e_out, const int* __restrict__ T,
    const float* __restrict__ gsums)
{
    const float inv0 = 1.0f / gsums[0];
    const float inv1 = 1.0f / gsums[1];
    const int n4 = NROWS / 4;
    const int stride = gridDim.x * blockDim.x;
    for (int i = blockIdx.x * blockDim.x + threadIdx.x; i < n4; i += stride) {
        float4 e = reinterpret_cast<const float4*>(e_out)[i];
        int4  t = reinterpret_cast<const int4*>(T)[i];
        e.x *= (t.x == 0) ? inv0 : inv1;
        e.y *= (t.y == 0) ? inv0 : inv1;
        e.z *= (t.z == 0) ? inv0 : inv1;
        e.w *= (t.w == 0) ? inv0 : inv1;
        reinterpret_cast<float4*>(e_out)[i] = e;
    }
}

extern "C" void kernel_launch(void* const* d_in, const int* in_sizes, int n_in,
                              void* d_out, int out_size, void* d_ws, size_t ws_size,
                              hipStream_t stream) {
    const float* x  = (const float*)d_in[0];
    const int*   T  = (const int*)d_in[1];
    const float* W1 = (const float*)d_in[2];
    const float* b1 = (const float*)d_in[3];
    const float* W2 = (const float*)d_in[4];
    const float* b2 = (const float*)d_in[5];
    float* e_out = (float*)d_out;
    float* gsums = (float*)d_ws;

    zero_sums_kernel<<<1, 64, 0, stream>>>(gsums);

    // 768 blocks x 256 thr = 3072 waves; 48 KB LDS, ~150 VGPR ->
    // 3 blocks/CU, 12 waves/CU (3/SIMD), all resident.
    fused_mfma_kernel<<<NBLK, BLOCK, 0, stream>>>(x, T, W1, b1, W2, b2, e_out, gsums);

    normalize_kernel<<<2048, 256, 0, stream>>>(e_out, T, gsums);
}